// Round 1
// baseline (555.984 us; speedup 1.0000x reference)
//
#include <hip/hip_runtime.h>
#include <hip/hip_bf16.h>
#include <math.h>

// Problem constants
#define Bb 2
#define Ss 2048
#define Hh 2048
#define NHh 16
#define HDd 128
#define Mm (Bb*Ss)   // 4096 tokens

typedef __bf16 bf16;
typedef __bf16 bf16x8 __attribute__((ext_vector_type(8)));
typedef __bf16 bf16x4 __attribute__((ext_vector_type(4)));
typedef float  f32x4  __attribute__((ext_vector_type(4)));

#define MFMA16(a,b,c) __builtin_amdgcn_mfma_f32_16x16x32_bf16((a),(b),(c),0,0,0)

__device__ __forceinline__ void gll16(const void* g, void* l) {
  __builtin_amdgcn_global_load_lds((__attribute__((address_space(1))) void*)g,
                                   (__attribute__((address_space(3))) void*)l, 16, 0, 0);
}

// ---------------- RoPE cos/sin tables: [S][64] each, fp32 ----------------
__global__ __launch_bounds__(256) void k_tables(float* __restrict__ cosT, float* __restrict__ sinT) {
  int id = blockIdx.x * 256 + threadIdx.x;   // S*64 threads
  int s = id >> 6, j = id & 63;
  float inv = 1.0f / powf(10000.0f, (float)j * (1.0f/64.0f));
  float a = (float)s * inv;
  cosT[id] = cosf(a);
  sinT[id] = sinf(a);
}

// ---------------- fp32 -> bf16 cast (4 elems/thread) ----------------
__global__ __launch_bounds__(256) void k_cvt(const float* __restrict__ in, bf16* __restrict__ out) {
  size_t i = ((size_t)blockIdx.x * 256 + threadIdx.x) * 4;
  float4 v = *(const float4*)(in + i);
  bf16x4 r = { (bf16)v.x, (bf16)v.y, (bf16)v.z, (bf16)v.w };
  *(bf16x4*)(out + i) = r;
}

// ---------------- GEMM: C[M x N] f32 = A[M x K] bf16 @ B[N x K]^T bf16 ----------------
// m97 structure: 128x128 tile, BK=64, 256 threads (2x2 waves of 64x64), global_load_lds w16.
__global__ __launch_bounds__(256) void k_gemm_bt(
    const bf16* __restrict__ A, const bf16* __restrict__ Bw,
    float* __restrict__ C, int M, int N, int K)
{
  __shared__ bf16 As[128*64];
  __shared__ bf16 Bs[128*64];
  const int tid = threadIdx.x;
  const int lane = tid & 63;
  const int w = tid >> 6, wm = w & 1, wn = w >> 1;
  const int mt = M >> 7;
  const int bm = blockIdx.x % mt, bn = blockIdx.x / mt;
  const int r8 = tid >> 3, c8 = tid & 7;          // staging: 32 rows/issue, 8 x 16B chunks/row
  const bf16* Ag = A  + (size_t)(bm*128 + r8) * K + c8*8;
  const bf16* Bg = Bw + (size_t)(bn*128 + r8) * K + c8*8;
  bf16* Asw = &As[r8*64 + c8*8];
  bf16* Bsw = &Bs[r8*64 + c8*8];

  f32x4 acc[4][4] = {};
  for (int k0 = 0; k0 < K; k0 += 64) {
#pragma unroll
    for (int i = 0; i < 4; ++i) {
      gll16(Ag + (size_t)i*32*K + k0, Asw + i*32*64);
      gll16(Bg + (size_t)i*32*K + k0, Bsw + i*32*64);
    }
    __syncthreads();   // drains vmcnt before barrier (m97 structure)
#pragma unroll
    for (int kc = 0; kc < 2; ++kc) {
      bf16x8 af[4], bfv[4];
#pragma unroll
      for (int mi = 0; mi < 4; ++mi)
        af[mi] = *(const bf16x8*)&As[(wm*64 + mi*16 + (lane & 15))*64 + kc*32 + (lane>>4)*8];
#pragma unroll
      for (int ni = 0; ni < 4; ++ni)
        bfv[ni] = *(const bf16x8*)&Bs[(wn*64 + ni*16 + (lane & 15))*64 + kc*32 + (lane>>4)*8];
#pragma unroll
      for (int mi = 0; mi < 4; ++mi)
#pragma unroll
        for (int ni = 0; ni < 4; ++ni)
          acc[mi][ni] = MFMA16(af[mi], bfv[ni], acc[mi][ni]);
    }
    __syncthreads();
  }
  // C/D layout (verified m89/m91): col = lane&15, row = (lane>>4)*4 + reg
#pragma unroll
  for (int mi = 0; mi < 4; ++mi)
#pragma unroll
    for (int ni = 0; ni < 4; ++ni) {
      int row0 = bm*128 + wm*64 + mi*16 + (lane>>4)*4;
      int col  = bn*128 + wn*64 + ni*16 + (lane & 15);
#pragma unroll
      for (int r = 0; r < 4; ++r)
        C[(size_t)(row0 + r) * N + col] = acc[mi][ni][r];
    }
}

// ---------------- RoPE: fp32 Q,K (B,S,NH,HD) -> bf16; 1/sqrt(HD) folded into Q ----------------
__global__ __launch_bounds__(256) void k_rope(
    const float* __restrict__ Qr, const float* __restrict__ Kr,
    const float* __restrict__ cosT, const float* __restrict__ sinT,
    bf16* __restrict__ Qb, bf16* __restrict__ Kb)
{
  const size_t id = (size_t)blockIdx.x * 256 + threadIdx.x;  // B*S*NH*64
  const int j = (int)(id & 63);
  const size_t row = id >> 6;                                 // (b*S+s)*NH+h
  const int s = (int)((row >> 4) & (Ss - 1));
  const float c = cosT[s*64 + j], sn = sinT[s*64 + j];
  const size_t base = row * HDd;
  const float scale = 0.08838834764831845f;  // 1/sqrt(128)
  float q1 = Qr[base + j], q2 = Qr[base + 64 + j];
  float k1 = Kr[base + j], k2 = Kr[base + 64 + j];
  Qb[base + j]      = (bf16)((q1*c - q2*sn) * scale);
  Qb[base + 64 + j] = (bf16)((q2*c + q1*sn) * scale);
  Kb[base + j]      = (bf16)(k1*c - k2*sn);
  Kb[base + 64 + j] = (bf16)(k2*c + k1*sn);
}

// ---------------- V transpose: fp32 (B,S,NH,HD) -> bf16 (B,NH,HD,S) ----------------
__global__ __launch_bounds__(256) void k_transpose_v(const float* __restrict__ V, bf16* __restrict__ Vt)
{
  __shared__ float T[64][65];
  const int blk = blockIdx.x;           // (B*NH) * (S/64) * (HD/64) = 32*32*2
  const int bh = blk >> 6;
  const int rem = blk & 63;
  const int s0 = (rem >> 1) * 64, d0 = (rem & 1) * 64;
  const int b = bh >> 4, h = bh & 15;
  const int t = threadIdx.x;
#pragma unroll
  for (int i = 0; i < 4; ++i) {
    int slot = i*256 + t;
    int row = slot >> 4, c4 = slot & 15;
    float4 v = *(const float4*)(V + ((size_t)(b*Ss + s0 + row) * NHh + h) * HDd + d0 + c4*4);
    T[row][c4*4+0] = v.x; T[row][c4*4+1] = v.y; T[row][c4*4+2] = v.z; T[row][c4*4+3] = v.w;
  }
  __syncthreads();
#pragma unroll
  for (int i = 0; i < 4; ++i) {
    int slot = i*256 + t;
    int dr = slot >> 4, sc = slot & 15;
    bf16x4 r = { (bf16)T[sc*4+0][dr], (bf16)T[sc*4+1][dr],
                 (bf16)T[sc*4+2][dr], (bf16)T[sc*4+3][dr] };
    *(bf16x4*)(Vt + ((size_t)bh * HDd + d0 + dr) * Ss + s0 + sc*4) = r;
  }
}

// ---------------- Flash attention: QBLK=64 (4 waves x 16 rows), KVBLK=64 ----------------
// K tile [64][128] and V^T tile [128][64] staged via global_load_lds with T2 XOR swizzle
// applied by pre-swizzling the GLOBAL source chunk (rule #21): chunk_src = chunk ^ (row&7).
__global__ __launch_bounds__(256) void k_attn(
    const bf16* __restrict__ Qb, const bf16* __restrict__ Kb,
    const bf16* __restrict__ Vt, bf16* __restrict__ Ob)
{
  __shared__ bf16 Ks[64*128];
  __shared__ bf16 Vs[128*64];
  __shared__ bf16 Ps[64*72];     // +8 pad: 144B row stride -> 2-way (free) on b128 reads
  const int blk = blockIdx.x;    // B*NH*(S/64) = 1024
  const int bh = blk >> 5;
  const int q0 = (blk & 31) * 64;
  const int b = bh >> 4, h = bh & 15;
  const int tid = threadIdx.x, lane = tid & 63, w = tid >> 6;

  // Q fragments in registers (A-operand: row=lane&15, k=(lane>>4)*8+j), scaled already
  bf16x8 aq[4];
  {
    const int qr = q0 + w*16 + (lane & 15);
    const bf16* qp = Qb + ((size_t)(b*Ss + qr) * NHh + h) * HDd + (lane>>4)*8;
#pragma unroll
    for (int kc = 0; kc < 4; ++kc) aq[kc] = *(const bf16x8*)(qp + kc*32);
  }
  float m_i[4], l_i[4];
  f32x4 o[8] = {};
#pragma unroll
  for (int i = 0; i < 4; ++i) { m_i[i] = -1e30f; l_i[i] = 0.f; }

  const int rK = tid >> 4, cK = tid & 15;   // K: 16 rows/issue, 16 chunks/row
  const int rV = tid >> 3, cV = tid & 7;    // V: 32 rows/issue,  8 chunks/row

  for (int kv0 = 0; kv0 < Ss; kv0 += 64) {
#pragma unroll
    for (int i = 0; i < 4; ++i) {
      const int rowK = i*16 + rK; const int sck = cK ^ (rowK & 7);
      gll16(Kb + ((size_t)(b*Ss + kv0 + rowK) * NHh + h) * HDd + sck*8, &Ks[rowK*128 + cK*8]);
      const int rowV = i*32 + rV; const int scv = cV ^ (rowV & 7);
      gll16(Vt + ((size_t)bh * HDd + rowV) * Ss + kv0 + scv*8, &Vs[rowV*64 + cV*8]);
    }
    __syncthreads();

    // S = Q K^T  (logits already scaled via Q)
    f32x4 sf[4];
#pragma unroll
    for (int nf = 0; nf < 4; ++nf) {
      f32x4 a = {0.f,0.f,0.f,0.f};
#pragma unroll
      for (int kc = 0; kc < 4; ++kc) {
        const int row = nf*16 + (lane & 15);
        const int ch  = kc*4 + (lane>>4);
        bf16x8 bk = *(const bf16x8*)&Ks[row*128 + (ch ^ (row & 7))*8];
        a = MFMA16(aq[kc], bk, a);
      }
      sf[nf] = a;
    }
    // online softmax (fp32); rows live in 16-lane groups, reduce with shfl_xor 1,2,4,8
    float c_i[4];
#pragma unroll
    for (int i = 0; i < 4; ++i) {
      float x = fmaxf(fmaxf(sf[0][i], sf[1][i]), fmaxf(sf[2][i], sf[3][i]));
      x = fmaxf(x, __shfl_xor(x, 1));
      x = fmaxf(x, __shfl_xor(x, 2));
      x = fmaxf(x, __shfl_xor(x, 4));
      x = fmaxf(x, __shfl_xor(x, 8));
      float mnew = fmaxf(m_i[i], x);
      c_i[i] = __expf(m_i[i] - mnew);
      m_i[i] = mnew;
    }
    float ps[4] = {0.f,0.f,0.f,0.f};
#pragma unroll
    for (int nf = 0; nf < 4; ++nf)
#pragma unroll
      for (int i = 0; i < 4; ++i) {
        float pv = __expf(sf[nf][i] - m_i[i]);
        sf[nf][i] = pv;
        ps[i] += pv;
      }
#pragma unroll
    for (int i = 0; i < 4; ++i) {
      float s = ps[i];
      s += __shfl_xor(s, 1); s += __shfl_xor(s, 2);
      s += __shfl_xor(s, 4); s += __shfl_xor(s, 8);
      l_i[i] = l_i[i] * c_i[i] + s;
    }
    // P -> LDS (bf16), per-wave-private 16-row band
#pragma unroll
    for (int nf = 0; nf < 4; ++nf)
#pragma unroll
      for (int i = 0; i < 4; ++i)
        Ps[(w*16 + (lane>>4)*4 + i)*72 + nf*16 + (lane & 15)] = (bf16)sf[nf][i];
    // rescale O
#pragma unroll
    for (int nfo = 0; nfo < 8; ++nfo)
#pragma unroll
      for (int i = 0; i < 4; ++i)
        o[nfo][i] *= c_i[i];
    // O += P V
#pragma unroll
    for (int kc = 0; kc < 2; ++kc) {
      bf16x8 pa = *(const bf16x8*)&Ps[(w*16 + (lane & 15))*72 + kc*32 + (lane>>4)*8];
#pragma unroll
      for (int nfo = 0; nfo < 8; ++nfo) {
        const int row = nfo*16 + (lane & 15);
        const int ch  = kc*4 + (lane>>4);
        bf16x8 bv = *(const bf16x8*)&Vs[row*64 + (ch ^ (row & 7))*8];
        o[nfo] = MFMA16(pa, bv, o[nfo]);
      }
    }
    __syncthreads();
  }
  // epilogue: normalize and store bf16 (B,S,NH,HD)
#pragma unroll
  for (int nfo = 0; nfo < 8; ++nfo)
#pragma unroll
    for (int i = 0; i < 4; ++i) {
      const int qr = q0 + w*16 + (lane>>4)*4 + i;
      const int d  = nfo*16 + (lane & 15);
      Ob[((size_t)(b*Ss + qr) * NHh + h) * HDd + d] = (bf16)(o[nfo][i] / l_i[i]);
    }
}

// ---------------- launcher ----------------
extern "C" void kernel_launch(void* const* d_in, const int* in_sizes, int n_in,
                              void* d_out, int out_size, void* d_ws, size_t ws_size,
                              hipStream_t stream) {
  (void)in_sizes; (void)n_in; (void)out_size; (void)ws_size;
  const float* X  = (const float*)d_in[0];
  const float* Wq = (const float*)d_in[1];
  const float* Wk = (const float*)d_in[2];
  const float* Wv = (const float*)d_in[3];
  const float* Wo = (const float*)d_in[4];
  float* out = (float*)d_out;

  char* p = (char*)d_ws;
  size_t off = 0;
  auto take = [&](size_t bytes) { char* r = p + off; off += (bytes + 255) & ~(size_t)255; return r; };

  float* cosT = (float*)take((size_t)Ss*64*4);
  float* sinT = (float*)take((size_t)Ss*64*4);
  bf16*  Xb   = (bf16*) take((size_t)Mm*Hh*2);
  bf16*  Wqb  = (bf16*) take((size_t)Hh*Hh*2);
  bf16*  Wkb  = (bf16*) take((size_t)Hh*Hh*2);
  bf16*  Wvb  = (bf16*) take((size_t)Hh*Hh*2);
  bf16*  Wob  = (bf16*) take((size_t)Hh*Hh*2);
  float* F1   = (float*)take((size_t)Mm*Hh*4);   // fp32 scratch (V, then Q)
  bf16*  Vt   = (bf16*) take((size_t)Mm*Hh*2);   // (B,NH,HD,S)
  bf16*  Qb2  = (bf16*) take((size_t)Mm*Hh*2);
  bf16*  Kb2  = (bf16*) take((size_t)Mm*Hh*2);
  bf16*  Ob   = (bf16*) take((size_t)Mm*Hh*2);
  float* F2   = out;                             // d_out doubles as K-proj fp32 scratch

  // 1. tables + casts
  k_tables<<<(Ss*64)/256, 256, 0, stream>>>(cosT, sinT);
  k_cvt<<<(Mm*Hh)/4/256, 256, 0, stream>>>(X,  Xb);
  k_cvt<<<(Hh*Hh)/4/256, 256, 0, stream>>>(Wq, Wqb);
  k_cvt<<<(Hh*Hh)/4/256, 256, 0, stream>>>(Wk, Wkb);
  k_cvt<<<(Hh*Hh)/4/256, 256, 0, stream>>>(Wv, Wvb);
  k_cvt<<<(Hh*Hh)/4/256, 256, 0, stream>>>(Wo, Wob);

  const int gemm_grid = (Mm/128) * (Hh/128);  // 512
  // 2. V projection -> F1, transpose -> Vt
  k_gemm_bt<<<gemm_grid, 256, 0, stream>>>(Xb, Wvb, F1, Mm, Hh, Hh);
  k_transpose_v<<<(Bb*NHh)*(Ss/64)*(HDd/64), 256, 0, stream>>>(F1, Vt);
  // 3. Q -> F1 (reuse), K -> F2 (=d_out scratch)
  k_gemm_bt<<<gemm_grid, 256, 0, stream>>>(Xb, Wqb, F1, Mm, Hh, Hh);
  k_gemm_bt<<<gemm_grid, 256, 0, stream>>>(Xb, Wkb, F2, Mm, Hh, Hh);
  // 4. RoPE -> bf16 Q (scaled), K
  k_rope<<<((size_t)Mm*NHh*64)/256, 256, 0, stream>>>(F1, F2, cosT, sinT, Qb2, Kb2);
  // 5. attention
  k_attn<<<Bb*NHh*(Ss/64), 256, 0, stream>>>(Qb2, Kb2, Vt, Ob);
  // 6. output projection -> d_out (fp32)
  k_gemm_bt<<<gemm_grid, 256, 0, stream>>>(Ob, Wob, out, Mm, Hh, Hh);
}

// Round 3
// 534.848 us; speedup vs baseline: 1.0395x; 1.0395x over previous
//
#include <hip/hip_runtime.h>
#include <hip/hip_bf16.h>
#include <math.h>

// Problem constants
#define Bb 2
#define Ss 2048
#define Hh 2048
#define NHh 16
#define HDd 128
#define Mm (Bb*Ss)   // 4096 tokens

typedef __bf16 bf16;
typedef __bf16 bf16x8 __attribute__((ext_vector_type(8)));
typedef __bf16 bf16x4 __attribute__((ext_vector_type(4)));
typedef float  f32x4  __attribute__((ext_vector_type(4)));

#define MFMA16(a,b,c) __builtin_amdgcn_mfma_f32_16x16x32_bf16((a),(b),(c),0,0,0)

__device__ __forceinline__ void gll16(const void* g, void* l) {
  __builtin_amdgcn_global_load_lds((__attribute__((address_space(1))) void*)g,
                                   (__attribute__((address_space(3))) void*)l, 16, 0, 0);
}

// ---------------- RoPE cos/sin tables: [S][64] each, fp32 ----------------
__global__ __launch_bounds__(256) void k_tables(float* __restrict__ cosT, float* __restrict__ sinT) {
  int id = blockIdx.x * 256 + threadIdx.x;   // S*64 threads
  int s = id >> 6, j = id & 63;
  float inv = 1.0f / powf(10000.0f, (float)j * (1.0f/64.0f));
  float a = (float)s * inv;
  cosT[id] = cosf(a);
  sinT[id] = sinf(a);
}

// ---------------- fp32 -> bf16 cast (4 elems/thread) ----------------
__global__ __launch_bounds__(256) void k_cvt(const float* __restrict__ in, bf16* __restrict__ out) {
  size_t i = ((size_t)blockIdx.x * 256 + threadIdx.x) * 4;
  float4 v = *(const float4*)(in + i);
  bf16x4 r = { (bf16)v.x, (bf16)v.y, (bf16)v.z, (bf16)v.w };
  *(bf16x4*)(out + i) = r;
}

// ---------------- GEMM: m97 structure, 128x128 tile, BK=64, 256 thr ----------------
// EPI=0: C fp32 row-major [M][N]
// EPI=1: QKV epilogue — cols <4096 -> QKb bf16 [M][4096]; cols >=4096 -> Vt bf16 (B,NH,HD,S)
template<int EPI>
__global__ __launch_bounds__(256) void k_gemm(
    const bf16* __restrict__ A, const bf16* __restrict__ Bw,
    float* __restrict__ C, bf16* __restrict__ QKb, bf16* __restrict__ Vt,
    int M, int N, int K)
{
  __shared__ bf16 As[128*64];
  __shared__ bf16 Bs[128*64];
  const int tid = threadIdx.x;
  const int lane = tid & 63;
  const int w = tid >> 6, wm = w & 1, wn = w >> 1;
  // XCD-aware chunked swizzle (grid % 8 == 0 for all our launches)
  const int cpx = gridDim.x >> 3;
  const int bid = (blockIdx.x & 7) * cpx + (blockIdx.x >> 3);
  const int mt = M >> 7;
  const int bm = bid % mt, bn = bid / mt;
  const int r8 = tid >> 3, c8 = tid & 7;          // staging: 32 rows/issue, 8 x 16B chunks/row
  const bf16* Ag = A  + (size_t)(bm*128 + r8) * K + c8*8;
  const bf16* Bg = Bw + (size_t)(bn*128 + r8) * K + c8*8;
  bf16* Asw = &As[r8*64 + c8*8];
  bf16* Bsw = &Bs[r8*64 + c8*8];

  f32x4 acc[4][4] = {};
  for (int k0 = 0; k0 < K; k0 += 64) {
#pragma unroll
    for (int i = 0; i < 4; ++i) {
      gll16(Ag + (size_t)i*32*K + k0, Asw + i*32*64);
      gll16(Bg + (size_t)i*32*K + k0, Bsw + i*32*64);
    }
    __syncthreads();
#pragma unroll
    for (int kc = 0; kc < 2; ++kc) {
      bf16x8 af[4], bfv[4];
#pragma unroll
      for (int mi = 0; mi < 4; ++mi)
        af[mi] = *(const bf16x8*)&As[(wm*64 + mi*16 + (lane & 15))*64 + kc*32 + (lane>>4)*8];
#pragma unroll
      for (int ni = 0; ni < 4; ++ni)
        bfv[ni] = *(const bf16x8*)&Bs[(wn*64 + ni*16 + (lane & 15))*64 + kc*32 + (lane>>4)*8];
#pragma unroll
      for (int mi = 0; mi < 4; ++mi)
#pragma unroll
        for (int ni = 0; ni < 4; ++ni)
          acc[mi][ni] = MFMA16(af[mi], bfv[ni], acc[mi][ni]);
    }
    __syncthreads();
  }
  // C/D layout: col = lane&15, row = (lane>>4)*4 + reg
  const int colB = bn*128 + wn*64;
  if (EPI == 0) {
#pragma unroll
    for (int mi = 0; mi < 4; ++mi)
#pragma unroll
      for (int ni = 0; ni < 4; ++ni) {
        int row0 = bm*128 + wm*64 + mi*16 + (lane>>4)*4;
        int col  = colB + ni*16 + (lane & 15);
#pragma unroll
        for (int r = 0; r < 4; ++r)
          C[(size_t)(row0 + r) * N + col] = acc[mi][ni][r];
      }
  } else if (colB < 4096) {   // Q or K slab -> bf16 [M][4096] (block-uniform branch)
#pragma unroll
    for (int mi = 0; mi < 4; ++mi)
#pragma unroll
      for (int ni = 0; ni < 4; ++ni) {
        int row0 = bm*128 + wm*64 + mi*16 + (lane>>4)*4;
        int col  = colB + ni*16 + (lane & 15);
#pragma unroll
        for (int r = 0; r < 4; ++r)
          QKb[(size_t)(row0 + r) * 4096 + col] = (bf16)acc[mi][ni][r];
      }
  } else {                    // V slab -> transposed bf16 (B,NH,HD,S), contiguous 8B stores
#pragma unroll
    for (int mi = 0; mi < 4; ++mi)
#pragma unroll
      for (int ni = 0; ni < 4; ++ni) {
        int row0 = bm*128 + wm*64 + mi*16 + (lane>>4)*4;
        int n2   = colB + ni*16 + (lane & 15) - 4096;   // h*128 + d
        int b = row0 >> 11, s0 = row0 & (Ss-1);
        bf16x4 pk = { (bf16)acc[mi][ni][0], (bf16)acc[mi][ni][1],
                      (bf16)acc[mi][ni][2], (bf16)acc[mi][ni][3] };
        *(bf16x4*)&Vt[((size_t)(b*NHh + (n2>>7))*HDd + (n2&127))*Ss + s0] = pk;
      }
  }
}

// ---------------- RoPE: bf16 QKb [M][4096] -> bf16 Qb (scaled), Kb in (B,S,NH,HD) ----------------
__global__ __launch_bounds__(256) void k_rope(
    const bf16* __restrict__ QKb,
    const float* __restrict__ cosT, const float* __restrict__ sinT,
    bf16* __restrict__ Qb, bf16* __restrict__ Kb)
{
  const size_t id = (size_t)blockIdx.x * 256 + threadIdx.x;  // B*S*NH*64
  const int j = (int)(id & 63);
  const size_t row = id >> 6;                // tok*16 + h
  const size_t tok = row >> 4;
  const int h = (int)(row & 15);
  const int s = (int)(tok & (Ss - 1));
  const float c = cosT[s*64 + j], sn = sinT[s*64 + j];
  const size_t qbase = tok * 4096 + h * 128;
  const float scale = 0.08838834764831845f;  // 1/sqrt(128)
  float q1 = (float)QKb[qbase + j],        q2 = (float)QKb[qbase + 64 + j];
  float k1 = (float)QKb[qbase + 2048 + j], k2 = (float)QKb[qbase + 2048 + 64 + j];
  const size_t obase = row * HDd;
  Qb[obase + j]      = (bf16)((q1*c - q2*sn) * scale);
  Qb[obase + 64 + j] = (bf16)((q2*c + q1*sn) * scale);
  Kb[obase + j]      = (bf16)(k1*c - k2*sn);
  Kb[obase + 64 + j] = (bf16)(k2*c + k1*sn);
}

// ---------------- Flash attention, 2-phase pipelined (T3-minimum) ----------------
// QBLK=64 (4 waves x 16 rows), KVBLK=64, K/V double-buffered in LDS with T2 swizzle
// via pre-swizzled GLOBAL source (rule #21). Raw s_barrier + asm vmcnt(0): stage for
// tile t+1 is issued BEFORE compute on tile t, drained once per tile at iter end.
__global__ __launch_bounds__(256) void k_attn(
    const bf16* __restrict__ Qb, const bf16* __restrict__ Kb,
    const bf16* __restrict__ Vt, bf16* __restrict__ Ob)
{
  __shared__ bf16 Ks[2][64*128];
  __shared__ bf16 Vs[2][128*64];
  __shared__ bf16 Ps[64*72];     // +8 pad
  // XCD swizzle: each XCD gets 128 contiguous logical blocks = 4 heads' full KV (4MB = L2)
  const int cpx = gridDim.x >> 3;
  const int blk = (blockIdx.x & 7) * cpx + (blockIdx.x >> 3);
  const int bh = blk >> 5;
  const int q0 = (blk & 31) * 64;
  const int b = bh >> 4, h = bh & 15;
  const int tid = threadIdx.x, lane = tid & 63, w = tid >> 6;

  const int rK = tid >> 4, cK = tid & 15;   // K: 16 rows/issue, 16 chunks/row
  const int rV = tid >> 3, cV = tid & 7;    // V: 32 rows/issue,  8 chunks/row
  const bf16* Kg0 = Kb + ((size_t)b*Ss*NHh + h) * HDd;
  const bf16* Vg0 = Vt + (size_t)bh * HDd * Ss;

  auto stage = [&](int bufi, int kv0) {
#pragma unroll
    for (int i = 0; i < 4; ++i) {
      const int rowK = i*16 + rK; const int sck = cK ^ (rowK & 7);
      gll16(Kg0 + (size_t)(kv0 + rowK)*(NHh*HDd) + sck*8, &Ks[bufi][rowK*128 + cK*8]);
      const int rowV = i*32 + rV; const int scv = cV ^ (rowV & 7);
      gll16(Vg0 + (size_t)rowV*Ss + kv0 + scv*8, &Vs[bufi][rowV*64 + cV*8]);
    }
  };

  // Q fragments in registers (scaled by 1/sqrt(HD) already)
  bf16x8 aq[4];
  {
    const int qr = q0 + w*16 + (lane & 15);
    const bf16* qp = Qb + ((size_t)(b*Ss + qr) * NHh + h) * HDd + (lane>>4)*8;
#pragma unroll
    for (int kc = 0; kc < 4; ++kc) aq[kc] = *(const bf16x8*)(qp + kc*32);
  }
  float m_i[4], l_i[4];
  f32x4 o[8] = {};
#pragma unroll
  for (int i = 0; i < 4; ++i) { m_i[i] = -1e30f; l_i[i] = 0.f; }

  stage(0, 0);
  asm volatile("s_waitcnt vmcnt(0)" ::: "memory");
  __builtin_amdgcn_s_barrier();
  asm volatile("" ::: "memory");

  const int NT = Ss / 64;
  for (int t = 0; t < NT; ++t) {
    const int cur = t & 1;
    if (t + 1 < NT) stage(cur ^ 1, (t + 1) * 64);   // prefetch next tile (not waited yet)

    // S = Q K^T (logits pre-scaled via Q)
    f32x4 sf[4];
    __builtin_amdgcn_s_setprio(1);
#pragma unroll
    for (int nf = 0; nf < 4; ++nf) {
      f32x4 a = {0.f,0.f,0.f,0.f};
#pragma unroll
      for (int kc = 0; kc < 4; ++kc) {
        const int row = nf*16 + (lane & 15);
        const int ch  = kc*4 + (lane>>4);
        bf16x8 bk = *(const bf16x8*)&Ks[cur][row*128 + (ch ^ (row & 7))*8];
        a = MFMA16(aq[kc], bk, a);
      }
      sf[nf] = a;
    }
    __builtin_amdgcn_s_setprio(0);

    // online softmax with defer-max (T13, THR=8)
    float x4[4];
#pragma unroll
    for (int i = 0; i < 4; ++i) {
      float x = fmaxf(fmaxf(sf[0][i], sf[1][i]), fmaxf(sf[2][i], sf[3][i]));
      x = fmaxf(x, __shfl_xor(x, 1));
      x = fmaxf(x, __shfl_xor(x, 2));
      x = fmaxf(x, __shfl_xor(x, 4));
      x = fmaxf(x, __shfl_xor(x, 8));
      x4[i] = x;
    }
    bool grow = (x4[0] > m_i[0] + 8.f) || (x4[1] > m_i[1] + 8.f) ||
                (x4[2] > m_i[2] + 8.f) || (x4[3] > m_i[3] + 8.f);
    if (__any(grow)) {
#pragma unroll
      for (int i = 0; i < 4; ++i) {
        float mnew = fmaxf(m_i[i], x4[i]);
        float c = __expf(m_i[i] - mnew);
        m_i[i] = mnew; l_i[i] *= c;
#pragma unroll
        for (int nfo = 0; nfo < 8; ++nfo) o[nfo][i] *= c;
      }
    }
    float ps[4] = {0.f,0.f,0.f,0.f};
#pragma unroll
    for (int nf = 0; nf < 4; ++nf)
#pragma unroll
      for (int i = 0; i < 4; ++i) {
        float pv = __expf(sf[nf][i] - m_i[i]);
        sf[nf][i] = pv;
        ps[i] += pv;
      }
#pragma unroll
    for (int i = 0; i < 4; ++i) {
      float s = ps[i];
      s += __shfl_xor(s, 1); s += __shfl_xor(s, 2);
      s += __shfl_xor(s, 4); s += __shfl_xor(s, 8);
      l_i[i] += s;
    }
    // P -> LDS (bf16), per-wave-private 16-row band
#pragma unroll
    for (int nf = 0; nf < 4; ++nf)
#pragma unroll
      for (int i = 0; i < 4; ++i)
        Ps[(w*16 + (lane>>4)*4 + i)*72 + nf*16 + (lane & 15)] = (bf16)sf[nf][i];

    // O += P V
    __builtin_amdgcn_s_setprio(1);
#pragma unroll
    for (int kc = 0; kc < 2; ++kc) {
      bf16x8 pa = *(const bf16x8*)&Ps[(w*16 + (lane & 15))*72 + kc*32 + (lane>>4)*8];
#pragma unroll
      for (int nfo = 0; nfo < 8; ++nfo) {
        const int row = nfo*16 + (lane & 15);
        const int ch  = kc*4 + (lane>>4);
        bf16x8 bv = *(const bf16x8*)&Vs[cur][row*64 + (ch ^ (row & 7))*8];
        o[nfo] = MFMA16(pa, bv, o[nfo]);
      }
    }
    __builtin_amdgcn_s_setprio(0);

    // next tile's loads must be complete before anyone computes on them,
    // and all waves must be done with buf[cur^1] reads (they are: uses precede this)
    asm volatile("s_waitcnt vmcnt(0)" ::: "memory");
    __builtin_amdgcn_s_barrier();
    asm volatile("" ::: "memory");
  }

  // epilogue: normalize and store bf16 (B,S,NH,HD)
#pragma unroll
  for (int nfo = 0; nfo < 8; ++nfo)
#pragma unroll
    for (int i = 0; i < 4; ++i) {
      const int qr = q0 + w*16 + (lane>>4)*4 + i;
      const int d  = nfo*16 + (lane & 15);
      Ob[((size_t)(b*Ss + qr) * NHh + h) * HDd + d] = (bf16)(o[nfo][i] / l_i[i]);
    }
}

// ---------------- launcher ----------------
extern "C" void kernel_launch(void* const* d_in, const int* in_sizes, int n_in,
                              void* d_out, int out_size, void* d_ws, size_t ws_size,
                              hipStream_t stream) {
  (void)in_sizes; (void)n_in; (void)out_size; (void)ws_size;
  const float* X  = (const float*)d_in[0];
  const float* Wq = (const float*)d_in[1];
  const float* Wk = (const float*)d_in[2];
  const float* Wv = (const float*)d_in[3];
  const float* Wo = (const float*)d_in[4];
  float* out = (float*)d_out;

  char* p = (char*)d_ws;
  size_t off = 0;
  auto take = [&](size_t bytes) { char* r = p + off; off += (bytes + 255) & ~(size_t)255; return r; };

  float* cosT = (float*)take((size_t)Ss*64*4);
  float* sinT = (float*)take((size_t)Ss*64*4);
  bf16*  Xb   = (bf16*) take((size_t)Mm*Hh*2);        // 16.8 MB
  bf16*  Wqkv = (bf16*) take((size_t)3*Hh*Hh*2);      // 25.2 MB [6144][2048]
  bf16*  Wob  = (bf16*) take((size_t)Hh*Hh*2);        //  8.4 MB
  bf16*  QKb  = (bf16*) take((size_t)Mm*4096*2);      // 33.6 MB [M][4096]
  bf16*  Vt   = (bf16*) take((size_t)Mm*Hh*2);        // 16.8 MB (B,NH,HD,S)
  bf16*  Qb   = (bf16*) take((size_t)Mm*Hh*2);
  bf16*  Kb2  = (bf16*) take((size_t)Mm*Hh*2);
  bf16*  Ob   = (bf16*) take((size_t)Mm*Hh*2);

  // 1. tables + casts (Wq/Wk/Wv concatenated row-wise into Wqkv)
  k_tables<<<(Ss*64)/256, 256, 0, stream>>>(cosT, sinT);
  k_cvt<<<(Mm*Hh)/4/256, 256, 0, stream>>>(X,  Xb);
  k_cvt<<<(Hh*Hh)/4/256, 256, 0, stream>>>(Wq, Wqkv);
  k_cvt<<<(Hh*Hh)/4/256, 256, 0, stream>>>(Wk, Wqkv + (size_t)Hh*Hh);
  k_cvt<<<(Hh*Hh)/4/256, 256, 0, stream>>>(Wv, Wqkv + (size_t)2*Hh*Hh);
  k_cvt<<<(Hh*Hh)/4/256, 256, 0, stream>>>(Wo, Wob);

  // 2. fused QKV projection: Q,K -> QKb bf16; V -> Vt transposed bf16
  k_gemm<1><<<(Mm/128) * (3*Hh/128), 256, 0, stream>>>(Xb, Wqkv, nullptr, QKb, Vt, Mm, 3*Hh, Hh);
  // 3. RoPE -> bf16 Q (scaled), K
  k_rope<<<((size_t)Mm*NHh*64)/256, 256, 0, stream>>>(QKb, cosT, sinT, Qb, Kb2);
  // 4. attention
  k_attn<<<Bb*NHh*(Ss/64), 256, 0, stream>>>(Qb, Kb2, Vt, Ob);
  // 5. output projection -> d_out (fp32)
  k_gemm<0><<<(Mm/128) * (Hh/128), 256, 0, stream>>>(Ob, Wob, out, nullptr, nullptr, Mm, Hh, Hh);
}

// Round 4
// 501.812 us; speedup vs baseline: 1.1080x; 1.0658x over previous
//
#include <hip/hip_runtime.h>
#include <hip/hip_bf16.h>
#include <math.h>

// Problem constants
#define Bb 2
#define Ss 2048
#define Hh 2048
#define NHh 16
#define HDd 128
#define Mm (Bb*Ss)   // 4096 tokens

typedef __bf16 bf16;
typedef __bf16 bf16x8 __attribute__((ext_vector_type(8)));
typedef __bf16 bf16x4 __attribute__((ext_vector_type(4)));
typedef float  f32x4  __attribute__((ext_vector_type(4)));

#define MFMA16(a,b,c) __builtin_amdgcn_mfma_f32_16x16x32_bf16((a),(b),(c),0,0,0)

__device__ __forceinline__ void gll16(const void* g, void* l) {
  __builtin_amdgcn_global_load_lds((__attribute__((address_space(1))) void*)g,
                                   (__attribute__((address_space(3))) void*)l, 16, 0, 0);
}

// ---------------- RoPE cos/sin tables: [S][64] each, fp32 ----------------
__global__ __launch_bounds__(256) void k_tables(float* __restrict__ cosT, float* __restrict__ sinT) {
  int id = blockIdx.x * 256 + threadIdx.x;   // S*64 threads
  int s = id >> 6, j = id & 63;
  float inv = 1.0f / powf(10000.0f, (float)j * (1.0f/64.0f));
  float a = (float)s * inv;
  cosT[id] = cosf(a);
  sinT[id] = sinf(a);
}

// ---------------- fp32 -> bf16 cast (4 elems/thread) ----------------
__global__ __launch_bounds__(256) void k_cvt(const float* __restrict__ in, bf16* __restrict__ out) {
  size_t i = ((size_t)blockIdx.x * 256 + threadIdx.x) * 4;
  float4 v = *(const float4*)(in + i);
  bf16x4 r = { (bf16)v.x, (bf16)v.y, (bf16)v.z, (bf16)v.w };
  *(bf16x4*)(out + i) = r;
}

// ---------------- GEMM: m97 structure, 128x128 tile, BK=64, 256 thr ----------------
// EPI=0: C fp32 row-major [M][N]
// EPI=1: QKV epilogue — cols <4096 -> QKb bf16 [M][4096]; cols >=4096 -> Vt bf16 (B,NH,HD,S)
template<int EPI>
__global__ __launch_bounds__(256) void k_gemm(
    const bf16* __restrict__ A, const bf16* __restrict__ Bw,
    float* __restrict__ C, bf16* __restrict__ QKb, bf16* __restrict__ Vt,
    int M, int N, int K)
{
  __shared__ bf16 As[128*64];
  __shared__ bf16 Bs[128*64];
  const int tid = threadIdx.x;
  const int lane = tid & 63;
  const int w = tid >> 6, wm = w & 1, wn = w >> 1;
  // XCD-aware chunked swizzle (grid % 8 == 0 for all our launches)
  const int cpx = gridDim.x >> 3;
  const int bid = (blockIdx.x & 7) * cpx + (blockIdx.x >> 3);
  const int mt = M >> 7;
  const int bm = bid % mt, bn = bid / mt;
  const int r8 = tid >> 3, c8 = tid & 7;          // staging: 32 rows/issue, 8 x 16B chunks/row
  const bf16* Ag = A  + (size_t)(bm*128 + r8) * K + c8*8;
  const bf16* Bg = Bw + (size_t)(bn*128 + r8) * K + c8*8;
  bf16* Asw = &As[r8*64 + c8*8];
  bf16* Bsw = &Bs[r8*64 + c8*8];

  f32x4 acc[4][4] = {};
  for (int k0 = 0; k0 < K; k0 += 64) {
#pragma unroll
    for (int i = 0; i < 4; ++i) {
      gll16(Ag + (size_t)i*32*K + k0, Asw + i*32*64);
      gll16(Bg + (size_t)i*32*K + k0, Bsw + i*32*64);
    }
    __syncthreads();
#pragma unroll
    for (int kc = 0; kc < 2; ++kc) {
      bf16x8 af[4], bfv[4];
#pragma unroll
      for (int mi = 0; mi < 4; ++mi)
        af[mi] = *(const bf16x8*)&As[(wm*64 + mi*16 + (lane & 15))*64 + kc*32 + (lane>>4)*8];
#pragma unroll
      for (int ni = 0; ni < 4; ++ni)
        bfv[ni] = *(const bf16x8*)&Bs[(wn*64 + ni*16 + (lane & 15))*64 + kc*32 + (lane>>4)*8];
#pragma unroll
      for (int mi = 0; mi < 4; ++mi)
#pragma unroll
        for (int ni = 0; ni < 4; ++ni)
          acc[mi][ni] = MFMA16(af[mi], bfv[ni], acc[mi][ni]);
    }
    __syncthreads();
  }
  // C/D layout: col = lane&15, row = (lane>>4)*4 + reg
  const int colB = bn*128 + wn*64;
  if (EPI == 0) {
#pragma unroll
    for (int mi = 0; mi < 4; ++mi)
#pragma unroll
      for (int ni = 0; ni < 4; ++ni) {
        int row0 = bm*128 + wm*64 + mi*16 + (lane>>4)*4;
        int col  = colB + ni*16 + (lane & 15);
#pragma unroll
        for (int r = 0; r < 4; ++r)
          C[(size_t)(row0 + r) * N + col] = acc[mi][ni][r];
      }
  } else if (colB < 4096) {   // Q or K slab -> bf16 [M][4096] (block-uniform branch)
#pragma unroll
    for (int mi = 0; mi < 4; ++mi)
#pragma unroll
      for (int ni = 0; ni < 4; ++ni) {
        int row0 = bm*128 + wm*64 + mi*16 + (lane>>4)*4;
        int col  = colB + ni*16 + (lane & 15);
#pragma unroll
        for (int r = 0; r < 4; ++r)
          QKb[(size_t)(row0 + r) * 4096 + col] = (bf16)acc[mi][ni][r];
      }
  } else {                    // V slab -> transposed bf16 (B,NH,HD,S), contiguous 8B stores
#pragma unroll
    for (int mi = 0; mi < 4; ++mi)
#pragma unroll
      for (int ni = 0; ni < 4; ++ni) {
        int row0 = bm*128 + wm*64 + mi*16 + (lane>>4)*4;
        int n2   = colB + ni*16 + (lane & 15) - 4096;   // h*128 + d
        int b = row0 >> 11, s0 = row0 & (Ss-1);
        bf16x4 pk = { (bf16)acc[mi][ni][0], (bf16)acc[mi][ni][1],
                      (bf16)acc[mi][ni][2], (bf16)acc[mi][ni][3] };
        *(bf16x4*)&Vt[((size_t)(b*NHh + (n2>>7))*HDd + (n2&127))*Ss + s0] = pk;
      }
  }
}

// ---------------- RoPE: bf16 QKb [M][4096] -> bf16 Qb (scaled), Kb in (B,S,NH,HD) ----------------
// Q scale = log2(e)/sqrt(HD): attention logits come out in base-2 units -> exp2 softmax.
__global__ __launch_bounds__(256) void k_rope(
    const bf16* __restrict__ QKb,
    const float* __restrict__ cosT, const float* __restrict__ sinT,
    bf16* __restrict__ Qb, bf16* __restrict__ Kb)
{
  const size_t id = (size_t)blockIdx.x * 256 + threadIdx.x;  // B*S*NH*64
  const int j = (int)(id & 63);
  const size_t row = id >> 6;                // tok*16 + h
  const size_t tok = row >> 4;
  const int h = (int)(row & 15);
  const int s = (int)(tok & (Ss - 1));
  const float c = cosT[s*64 + j], sn = sinT[s*64 + j];
  const size_t qbase = tok * 4096 + h * 128;
  const float scale = 0.12753102543421936f;  // log2(e)/sqrt(128)
  float q1 = (float)QKb[qbase + j],        q2 = (float)QKb[qbase + 64 + j];
  float k1 = (float)QKb[qbase + 2048 + j], k2 = (float)QKb[qbase + 2048 + 64 + j];
  const size_t obase = row * HDd;
  Qb[obase + j]      = (bf16)((q1*c - q2*sn) * scale);
  Qb[obase + 64 + j] = (bf16)((q2*c + q1*sn) * scale);
  Kb[obase + j]      = (bf16)(k1*c - k2*sn);
  Kb[obase + 64 + j] = (bf16)(k2*c + k1*sn);
}

// ---------------- Flash attention, 2-phase pipelined, lazy-softmax ----------------
// QBLK=64 (4 waves x 16 rows), KVBLK=64, K/V double-buffered LDS, T2 swizzle via
// pre-swizzled global source. Steady-state tile has ZERO cross-lane ops: per-lane
// max + defer-max gate (THR=11.5 bits); l-sum kept as per-lane partials, reduced
// once after the KV loop. Logits are base-2 (log2e folded into Q).
__global__ __launch_bounds__(256) void k_attn(
    const bf16* __restrict__ Qb, const bf16* __restrict__ Kb,
    const bf16* __restrict__ Vt, bf16* __restrict__ Ob)
{
  __shared__ bf16 Ks[2][64*128];
  __shared__ bf16 Vs[2][128*64];
  __shared__ bf16 Ps[64*72];     // +8 pad
  // XCD swizzle: each XCD gets 128 contiguous logical blocks = 4 heads' full KV (4MB = L2)
  const int cpx = gridDim.x >> 3;
  const int blk = (blockIdx.x & 7) * cpx + (blockIdx.x >> 3);
  const int bh = blk >> 5;
  const int q0 = (blk & 31) * 64;
  const int b = bh >> 4, h = bh & 15;
  const int tid = threadIdx.x, lane = tid & 63, w = tid >> 6;

  const int rK = tid >> 4, cK = tid & 15;   // K: 16 rows/issue, 16 chunks/row
  const int rV = tid >> 3, cV = tid & 7;    // V: 32 rows/issue,  8 chunks/row
  const bf16* Kg0 = Kb + ((size_t)b*Ss*NHh + h) * HDd;
  const bf16* Vg0 = Vt + (size_t)bh * HDd * Ss;

  auto stage = [&](int bufi, int kv0) {
#pragma unroll
    for (int i = 0; i < 4; ++i) {
      const int rowK = i*16 + rK; const int sck = cK ^ (rowK & 7);
      gll16(Kg0 + (size_t)(kv0 + rowK)*(NHh*HDd) + sck*8, &Ks[bufi][rowK*128 + cK*8]);
      const int rowV = i*32 + rV; const int scv = cV ^ (rowV & 7);
      gll16(Vg0 + (size_t)rowV*Ss + kv0 + scv*8, &Vs[bufi][rowV*64 + cV*8]);
    }
  };

  // Q fragments in registers (pre-scaled by log2e/sqrt(HD))
  bf16x8 aq[4];
  {
    const int qr = q0 + w*16 + (lane & 15);
    const bf16* qp = Qb + ((size_t)(b*Ss + qr) * NHh + h) * HDd + (lane>>4)*8;
#pragma unroll
    for (int kc = 0; kc < 4; ++kc) aq[kc] = *(const bf16x8*)(qp + kc*32);
  }
  float m_i[4], l_par[4];
  f32x4 o[8] = {};
#pragma unroll
  for (int i = 0; i < 4; ++i) { m_i[i] = -1e30f; l_par[i] = 0.f; }

  stage(0, 0);
  asm volatile("s_waitcnt vmcnt(0)" ::: "memory");
  __builtin_amdgcn_s_barrier();
  asm volatile("" ::: "memory");

  const int NT = Ss / 64;
  for (int t = 0; t < NT; ++t) {
    const int cur = t & 1;
    if (t + 1 < NT) stage(cur ^ 1, (t + 1) * 64);   // prefetch next tile (not waited yet)

    // S = Q K^T (base-2 logits)
    f32x4 sf[4];
    __builtin_amdgcn_s_setprio(1);
#pragma unroll
    for (int nf = 0; nf < 4; ++nf) {
      f32x4 a = {0.f,0.f,0.f,0.f};
#pragma unroll
      for (int kc = 0; kc < 4; ++kc) {
        const int row = nf*16 + (lane & 15);
        const int ch  = kc*4 + (lane>>4);
        bf16x8 bk = *(const bf16x8*)&Ks[cur][row*128 + (ch ^ (row & 7))*8];
        a = MFMA16(aq[kc], bk, a);
      }
      sf[nf] = a;
    }
    __builtin_amdgcn_s_setprio(0);

    // lazy online softmax: per-lane max only; cross-lane reduce only on growth
    float xl[4];
#pragma unroll
    for (int i = 0; i < 4; ++i)
      xl[i] = fmaxf(fmaxf(sf[0][i], sf[1][i]), fmaxf(sf[2][i], sf[3][i]));
    bool grow = (xl[0] > m_i[0] + 11.5f) || (xl[1] > m_i[1] + 11.5f) ||
                (xl[2] > m_i[2] + 11.5f) || (xl[3] > m_i[3] + 11.5f);
    if (__any(grow)) {
#pragma unroll
      for (int i = 0; i < 4; ++i) {
        float x = xl[i];
        x = fmaxf(x, __shfl_xor(x, 1));
        x = fmaxf(x, __shfl_xor(x, 2));
        x = fmaxf(x, __shfl_xor(x, 4));
        x = fmaxf(x, __shfl_xor(x, 8));
        float mnew = fmaxf(m_i[i], x);
        float c = exp2f(m_i[i] - mnew);
        m_i[i] = mnew; l_par[i] *= c;
#pragma unroll
        for (int nfo = 0; nfo < 8; ++nfo) o[nfo][i] *= c;
      }
    }
#pragma unroll
    for (int nf = 0; nf < 4; ++nf)
#pragma unroll
      for (int i = 0; i < 4; ++i) {
        float pv = exp2f(sf[nf][i] - m_i[i]);   // bounded by 2^11.5
        sf[nf][i] = pv;
        l_par[i] += pv;
      }
    // P -> LDS (bf16), per-wave-private 16-row band
#pragma unroll
    for (int nf = 0; nf < 4; ++nf)
#pragma unroll
      for (int i = 0; i < 4; ++i)
        Ps[(w*16 + (lane>>4)*4 + i)*72 + nf*16 + (lane & 15)] = (bf16)sf[nf][i];

    // O += P V
    __builtin_amdgcn_s_setprio(1);
#pragma unroll
    for (int kc = 0; kc < 2; ++kc) {
      bf16x8 pa = *(const bf16x8*)&Ps[(w*16 + (lane & 15))*72 + kc*32 + (lane>>4)*8];
#pragma unroll
      for (int nfo = 0; nfo < 8; ++nfo) {
        const int row = nfo*16 + (lane & 15);
        const int ch  = kc*4 + (lane>>4);
        bf16x8 bv = *(const bf16x8*)&Vs[cur][row*64 + (ch ^ (row & 7))*8];
        o[nfo] = MFMA16(pa, bv, o[nfo]);
      }
    }
    __builtin_amdgcn_s_setprio(0);

    // next tile's loads must be complete before anyone computes on them,
    // and all waves must be done with buf[cur^1] reads (they are: uses precede this)
    asm volatile("s_waitcnt vmcnt(0)" ::: "memory");
    __builtin_amdgcn_s_barrier();
    asm volatile("" ::: "memory");
  }

  // final l reduce (once) + epilogue: normalize and store bf16 (B,S,NH,HD)
  float linv[4];
#pragma unroll
  for (int i = 0; i < 4; ++i) {
    float s = l_par[i];
    s += __shfl_xor(s, 1); s += __shfl_xor(s, 2);
    s += __shfl_xor(s, 4); s += __shfl_xor(s, 8);
    linv[i] = 1.0f / s;
  }
#pragma unroll
  for (int nfo = 0; nfo < 8; ++nfo)
#pragma unroll
    for (int i = 0; i < 4; ++i) {
      const int qr = q0 + w*16 + (lane>>4)*4 + i;
      const int d  = nfo*16 + (lane & 15);
      Ob[((size_t)(b*Ss + qr) * NHh + h) * HDd + d] = (bf16)(o[nfo][i] * linv[i]);
    }
}

// ---------------- launcher ----------------
extern "C" void kernel_launch(void* const* d_in, const int* in_sizes, int n_in,
                              void* d_out, int out_size, void* d_ws, size_t ws_size,
                              hipStream_t stream) {
  (void)in_sizes; (void)n_in; (void)out_size; (void)ws_size;
  const float* X  = (const float*)d_in[0];
  const float* Wq = (const float*)d_in[1];
  const float* Wk = (const float*)d_in[2];
  const float* Wv = (const float*)d_in[3];
  const float* Wo = (const float*)d_in[4];
  float* out = (float*)d_out;

  char* p = (char*)d_ws;
  size_t off = 0;
  auto take = [&](size_t bytes) { char* r = p + off; off += (bytes + 255) & ~(size_t)255; return r; };

  float* cosT = (float*)take((size_t)Ss*64*4);
  float* sinT = (float*)take((size_t)Ss*64*4);
  bf16*  Xb   = (bf16*) take((size_t)Mm*Hh*2);        // 16.8 MB
  bf16*  Wqkv = (bf16*) take((size_t)3*Hh*Hh*2);      // 25.2 MB [6144][2048]
  bf16*  Wob  = (bf16*) take((size_t)Hh*Hh*2);        //  8.4 MB
  bf16*  QKb  = (bf16*) take((size_t)Mm*4096*2);      // 33.6 MB [M][4096]
  bf16*  Vt   = (bf16*) take((size_t)Mm*Hh*2);        // 16.8 MB (B,NH,HD,S)
  bf16*  Qb   = (bf16*) take((size_t)Mm*Hh*2);
  bf16*  Kb2  = (bf16*) take((size_t)Mm*Hh*2);
  bf16*  Ob   = (bf16*) take((size_t)Mm*Hh*2);

  // 1. tables + casts (Wq/Wk/Wv concatenated row-wise into Wqkv)
  k_tables<<<(Ss*64)/256, 256, 0, stream>>>(cosT, sinT);
  k_cvt<<<(Mm*Hh)/4/256, 256, 0, stream>>>(X,  Xb);
  k_cvt<<<(Hh*Hh)/4/256, 256, 0, stream>>>(Wq, Wqkv);
  k_cvt<<<(Hh*Hh)/4/256, 256, 0, stream>>>(Wk, Wqkv + (size_t)Hh*Hh);
  k_cvt<<<(Hh*Hh)/4/256, 256, 0, stream>>>(Wv, Wqkv + (size_t)2*Hh*Hh);
  k_cvt<<<(Hh*Hh)/4/256, 256, 0, stream>>>(Wo, Wob);

  // 2. fused QKV projection: Q,K -> QKb bf16; V -> Vt transposed bf16
  k_gemm<1><<<(Mm/128) * (3*Hh/128), 256, 0, stream>>>(Xb, Wqkv, nullptr, QKb, Vt, Mm, 3*Hh, Hh);
  // 3. RoPE -> bf16 Q (scaled by log2e/sqrt(HD)), K
  k_rope<<<((size_t)Mm*NHh*64)/256, 256, 0, stream>>>(QKb, cosT, sinT, Qb, Kb2);
  // 4. attention
  k_attn<<<Bb*NHh*(Ss/64), 256, 0, stream>>>(Qb, Kb2, Vt, Ob);
  // 5. output projection -> d_out (fp32)
  k_gemm<0><<<(Mm/128) * (Hh/128), 256, 0, stream>>>(Ob, Wob, out, nullptr, nullptr, Mm, Hh, Hh);
}

// Round 5
// 465.902 us; speedup vs baseline: 1.1933x; 1.0771x over previous
//
#include <hip/hip_runtime.h>
#include <hip/hip_bf16.h>
#include <math.h>

// Problem constants
#define Bb 2
#define Ss 2048
#define Hh 2048
#define NHh 16
#define HDd 128
#define Mm (Bb*Ss)   // 4096 tokens

typedef __bf16 bf16;
typedef __bf16 bf16x8 __attribute__((ext_vector_type(8)));
typedef __bf16 bf16x4 __attribute__((ext_vector_type(4)));
typedef float  f32x4  __attribute__((ext_vector_type(4)));

#define MFMA16(a,b,c) __builtin_amdgcn_mfma_f32_16x16x32_bf16((a),(b),(c),0,0,0)

__device__ __forceinline__ void gll16(const void* g, void* l) {
  __builtin_amdgcn_global_load_lds((__attribute__((address_space(1))) void*)g,
                                   (__attribute__((address_space(3))) void*)l, 16, 0, 0);
}

// ---------------- RoPE cos/sin tables: [S][64] each, fp32 ----------------
__global__ __launch_bounds__(256) void k_tables(float* __restrict__ cosT, float* __restrict__ sinT) {
  int id = blockIdx.x * 256 + threadIdx.x;   // S*64 threads
  int s = id >> 6, j = id & 63;
  float inv = 1.0f / powf(10000.0f, (float)j * (1.0f/64.0f));
  float a = (float)s * inv;
  cosT[id] = cosf(a);
  sinT[id] = sinf(a);
}

// ---------------- fp32 -> bf16 cast (4 elems/thread) ----------------
__global__ __launch_bounds__(256) void k_cvt(const float* __restrict__ in, bf16* __restrict__ out) {
  size_t i = ((size_t)blockIdx.x * 256 + threadIdx.x) * 4;
  float4 v = *(const float4*)(in + i);
  bf16x4 r = { (bf16)v.x, (bf16)v.y, (bf16)v.z, (bf16)v.w };
  *(bf16x4*)(out + i) = r;
}

// ---------------- QKV GEMM: 256x256 tile, BK=64, 8-phase counted-vmcnt (T2+T3+T4+T5) ----
// 512 thr = 8 waves (2M x 4N), per-wave out 128x64 (acc[8][4] f32x4). LDS 128 KiB:
// As/Bs [2 dbuf][256][64] bf16, T2 XOR-swizzle (chunk ^= row&7) applied on BOTH the
// pre-swizzled global source of global_load_lds (rule #21) and the ds_read address.
// Stage schedule (derived; each half-tile staged only after its region's last reader
// passed an end-of-phase barrier with lgkmcnt(0) drained):
//   ph0: d1.A-lo <- kt(2it+1)   ph1: d1.A-hi <- kt(2it+1)     [just-in-time A]
//   ph2: d0.B-lo <- kt(2it+2)   ph3: d0.B-hi                  [d0.B consumed ph0]
//   ph4: d0.A-lo <- kt(2it+2)   ph5: d0.A-hi                  [d0.A consumed ph0-3]
//   ph6: d1.B-lo <- kt(2it+3)   ph7: d1.B-hi                  [d1.B consumed ph4]
// Waits: vmcnt(4) end of ph3 (allows ph2/3 stages outstanding; guarantees d1.A landed)
//        vmcnt(4) end of ph7 (allows ph6/7 stages outstanding; guarantees d0 landed)
// Epilogue: cols<4096 -> QKb bf16 [M][4096]; cols>=4096 -> Vt bf16 (B,NH,HD,S).
__global__ __launch_bounds__(512, 2) void k_gemm8_qkv(
    const bf16* __restrict__ A, const bf16* __restrict__ Bw,
    bf16* __restrict__ QKb, bf16* __restrict__ Vt)
{
  constexpr int K = Hh;            // 2048
  constexpr int NT = K / 64;       // 32 K-tiles
  constexpr int NITER = NT / 2;    // 16 iterations (2 K-tiles each)
  __shared__ bf16 As[2][16384];    // [dbuf][256*64]
  __shared__ bf16 Bs[2][16384];
  const int tid = threadIdx.x;
  const int lane = tid & 63;
  const int w = tid >> 6;          // 0..7
  const int wm = w >> 2, wn = w & 3;
  const int l15 = lane & 15, l4 = lane >> 4;
  // XCD-aware chunked swizzle (grid 384 % 8 == 0)
  const int cpx = gridDim.x >> 3;
  const int bid = (blockIdx.x & 7) * cpx + (blockIdx.x >> 3);
  const int bm = bid & 15, bn = bid >> 4;   // mt = M/256 = 16

  auto stageHalf = [&](int d, int isB, int half, int kt) {
    const bf16* g = isB ? Bw : A;
    const int rowbase = (isB ? bn : bm) * 256 + half * 128;
    bf16* lb = isB ? &Bs[d][half*8192] : &As[d][half*8192];
#pragma unroll
    for (int issue = 0; issue < 2; ++issue) {
      int slot = issue*512 + tid;        // 0..1023 (16B units of the 16KB half)
      int r = slot >> 3, c = slot & 7;   // row in half, 16B chunk
      int cs = c ^ (r & 7);              // pre-swizzled global chunk
      gll16(g + (size_t)(rowbase + r) * K + kt*64 + cs*8, lb + slot*8);
    }
  };

  f32x4 acc[8][4] = {};
  bf16x8 bfr[4][2];

  // prologue: k-tile 0 fully, k-tile 1 B halves (A halves are just-in-time at ph0/1)
  stageHalf(0,0,0,0); stageHalf(0,0,1,0);
  stageHalf(0,1,0,0); stageHalf(0,1,1,0);
  stageHalf(1,1,0,1); stageHalf(1,1,1,1);
  asm volatile("s_waitcnt vmcnt(0)" ::: "memory");
  __builtin_amdgcn_s_barrier();

  for (int it = 0; it < NITER; ++it) {
    const int more = (it < NITER-1);
    const int kt1 = 2*it+1, kt2 = 2*it+2, kt3 = 2*it+3;
#pragma unroll
    for (int hp = 0; hp < 2; ++hp) {       // dbuf: 0 = even K-tile, 1 = odd
#pragma unroll
      for (int q = 0; q < 4; ++q) {        // quadrant = M-frag pair {2q, 2q+1}
        if (q == 0) {                      // B fragments for this K-tile (8 x b128)
#pragma unroll
          for (int nf = 0; nf < 4; ++nf)
#pragma unroll
            for (int kc = 0; kc < 2; ++kc) {
              int row = wn*64 + nf*16 + l15;
              int ch  = kc*4 + l4;
              bfr[nf][kc] = *(const bf16x8*)&Bs[hp][row*64 + ((ch ^ (row & 7))*8)];
            }
        }
        bf16x8 afr[2][2];                  // A fragments (4 x b128)
#pragma unroll
        for (int i = 0; i < 2; ++i)
#pragma unroll
          for (int kc = 0; kc < 2; ++kc) {
            int row = wm*128 + (q*2+i)*16 + l15;
            int ch  = kc*4 + l4;
            afr[i][kc] = *(const bf16x8*)&As[hp][row*64 + ((ch ^ (row & 7))*8)];
          }
        // stage one half-tile per the schedule above
        const int ph = hp*4 + q;
        if      (ph == 0)      stageHalf(1,0,0,kt1);
        else if (ph == 1)      stageHalf(1,0,1,kt1);
        else if (more) {
          if      (ph == 2)    stageHalf(0,1,0,kt2);
          else if (ph == 3)    stageHalf(0,1,1,kt2);
          else if (ph == 4)    stageHalf(0,0,0,kt2);
          else if (ph == 5)    stageHalf(0,0,1,kt2);
          else if (ph == 6)    stageHalf(1,1,0,kt3);
          else                 stageHalf(1,1,1,kt3);
        }
        __builtin_amdgcn_s_barrier();      // mid-phase barrier
        __builtin_amdgcn_s_setprio(1);
#pragma unroll
        for (int i = 0; i < 2; ++i)
#pragma unroll
          for (int nf = 0; nf < 4; ++nf)
#pragma unroll
            for (int kc = 0; kc < 2; ++kc)
              acc[q*2+i][nf] = MFMA16(afr[i][kc], bfr[nf][kc], acc[q*2+i][nf]);
        __builtin_amdgcn_s_setprio(0);
        asm volatile("s_waitcnt lgkmcnt(0)" ::: "memory");   // all ds_reads drained
        __builtin_amdgcn_sched_barrier(0);                    // rule #18 fence
        if (ph == 3) {
          if (more) asm volatile("s_waitcnt vmcnt(4)" ::: "memory");
          else      asm volatile("s_waitcnt vmcnt(0)" ::: "memory");
        } else if (ph == 7 && more) {
          asm volatile("s_waitcnt vmcnt(4)" ::: "memory");
        }
        __builtin_amdgcn_s_barrier();      // end-of-phase barrier
      }
    }
  }

  // epilogue: C/D layout col=lane&15, row=(lane>>4)*4+reg
  const int col0 = bn*256;
  if (col0 < 4096) {        // Q or K slab (block-uniform)
#pragma unroll
    for (int mf = 0; mf < 8; ++mf)
#pragma unroll
      for (int nf = 0; nf < 4; ++nf) {
        int row0 = bm*256 + wm*128 + mf*16 + l4*4;
        int col  = col0 + wn*64 + nf*16 + l15;
#pragma unroll
        for (int r = 0; r < 4; ++r)
          QKb[(size_t)(row0 + r) * 4096 + col] = (bf16)acc[mf][nf][r];
      }
  } else {                  // V slab -> transposed bf16 (B,NH,HD,S), 8B stores
#pragma unroll
    for (int mf = 0; mf < 8; ++mf)
#pragma unroll
      for (int nf = 0; nf < 4; ++nf) {
        int row0 = bm*256 + wm*128 + mf*16 + l4*4;
        int n2   = col0 + wn*64 + nf*16 + l15 - 4096;   // h*128 + d
        int b = row0 >> 11, s0 = row0 & (Ss-1);
        bf16x4 pk = { (bf16)acc[mf][nf][0], (bf16)acc[mf][nf][1],
                      (bf16)acc[mf][nf][2], (bf16)acc[mf][nf][3] };
        *(bf16x4*)&Vt[((size_t)(b*NHh + (n2>>7))*HDd + (n2&127))*Ss + s0] = pk;
      }
  }
}

// ---------------- Wo GEMM: m97 structure, 128x128 tile, fp32 C ----------------
__global__ __launch_bounds__(256) void k_gemm_f32(
    const bf16* __restrict__ A, const bf16* __restrict__ Bw,
    float* __restrict__ C, int M, int N, int K)
{
  __shared__ bf16 As[128*64];
  __shared__ bf16 Bs[128*64];
  const int tid = threadIdx.x;
  const int lane = tid & 63;
  const int w = tid >> 6, wm = w & 1, wn = w >> 1;
  const int cpx = gridDim.x >> 3;
  const int bid = (blockIdx.x & 7) * cpx + (blockIdx.x >> 3);
  const int mt = M >> 7;
  const int bm = bid % mt, bn = bid / mt;
  const int r8 = tid >> 3, c8 = tid & 7;
  const bf16* Ag = A  + (size_t)(bm*128 + r8) * K + c8*8;
  const bf16* Bg = Bw + (size_t)(bn*128 + r8) * K + c8*8;
  bf16* Asw = &As[r8*64 + c8*8];
  bf16* Bsw = &Bs[r8*64 + c8*8];

  f32x4 acc[4][4] = {};
  for (int k0 = 0; k0 < K; k0 += 64) {
#pragma unroll
    for (int i = 0; i < 4; ++i) {
      gll16(Ag + (size_t)i*32*K + k0, Asw + i*32*64);
      gll16(Bg + (size_t)i*32*K + k0, Bsw + i*32*64);
    }
    __syncthreads();
#pragma unroll
    for (int kc = 0; kc < 2; ++kc) {
      bf16x8 af[4], bfv[4];
#pragma unroll
      for (int mi = 0; mi < 4; ++mi)
        af[mi] = *(const bf16x8*)&As[(wm*64 + mi*16 + (lane & 15))*64 + kc*32 + (lane>>4)*8];
#pragma unroll
      for (int ni = 0; ni < 4; ++ni)
        bfv[ni] = *(const bf16x8*)&Bs[(wn*64 + ni*16 + (lane & 15))*64 + kc*32 + (lane>>4)*8];
#pragma unroll
      for (int mi = 0; mi < 4; ++mi)
#pragma unroll
        for (int ni = 0; ni < 4; ++ni)
          acc[mi][ni] = MFMA16(af[mi], bfv[ni], acc[mi][ni]);
    }
    __syncthreads();
  }
#pragma unroll
  for (int mi = 0; mi < 4; ++mi)
#pragma unroll
    for (int ni = 0; ni < 4; ++ni) {
      int row0 = bm*128 + wm*64 + mi*16 + (lane>>4)*4;
      int col  = bn*128 + wn*64 + ni*16 + (lane & 15);
#pragma unroll
      for (int r = 0; r < 4; ++r)
        C[(size_t)(row0 + r) * N + col] = acc[mi][ni][r];
    }
}

// ---------------- RoPE: bf16 QKb [M][4096] -> bf16 Qb (scaled), Kb in (B,S,NH,HD) ----------------
// Q scale = log2(e)/sqrt(HD): attention logits come out in base-2 units -> exp2 softmax.
__global__ __launch_bounds__(256) void k_rope(
    const bf16* __restrict__ QKb,
    const float* __restrict__ cosT, const float* __restrict__ sinT,
    bf16* __restrict__ Qb, bf16* __restrict__ Kb)
{
  const size_t id = (size_t)blockIdx.x * 256 + threadIdx.x;  // B*S*NH*64
  const int j = (int)(id & 63);
  const size_t row = id >> 6;                // tok*16 + h
  const size_t tok = row >> 4;
  const int h = (int)(row & 15);
  const int s = (int)(tok & (Ss - 1));
  const float c = cosT[s*64 + j], sn = sinT[s*64 + j];
  const size_t qbase = tok * 4096 + h * 128;
  const float scale = 0.12753102543421936f;  // log2(e)/sqrt(128)
  float q1 = (float)QKb[qbase + j],        q2 = (float)QKb[qbase + 64 + j];
  float k1 = (float)QKb[qbase + 2048 + j], k2 = (float)QKb[qbase + 2048 + 64 + j];
  const size_t obase = row * HDd;
  Qb[obase + j]      = (bf16)((q1*c - q2*sn) * scale);
  Qb[obase + 64 + j] = (bf16)((q2*c + q1*sn) * scale);
  Kb[obase + j]      = (bf16)(k1*c - k2*sn);
  Kb[obase + 64 + j] = (bf16)(k2*c + k1*sn);
}

// ---------------- Flash attention, 2-phase pipelined, lazy-softmax ----------------
__global__ __launch_bounds__(256) void k_attn(
    const bf16* __restrict__ Qb, const bf16* __restrict__ Kb,
    const bf16* __restrict__ Vt, bf16* __restrict__ Ob)
{
  __shared__ bf16 Ks[2][64*128];
  __shared__ bf16 Vs[2][128*64];
  __shared__ bf16 Ps[64*72];     // +8 pad
  const int cpx = gridDim.x >> 3;
  const int blk = (blockIdx.x & 7) * cpx + (blockIdx.x >> 3);
  const int bh = blk >> 5;
  const int q0 = (blk & 31) * 64;
  const int b = bh >> 4, h = bh & 15;
  const int tid = threadIdx.x, lane = tid & 63, w = tid >> 6;

  const int rK = tid >> 4, cK = tid & 15;
  const int rV = tid >> 3, cV = tid & 7;
  const bf16* Kg0 = Kb + ((size_t)b*Ss*NHh + h) * HDd;
  const bf16* Vg0 = Vt + (size_t)bh * HDd * Ss;

  auto stage = [&](int bufi, int kv0) {
#pragma unroll
    for (int i = 0; i < 4; ++i) {
      const int rowK = i*16 + rK; const int sck = cK ^ (rowK & 7);
      gll16(Kg0 + (size_t)(kv0 + rowK)*(NHh*HDd) + sck*8, &Ks[bufi][rowK*128 + cK*8]);
      const int rowV = i*32 + rV; const int scv = cV ^ (rowV & 7);
      gll16(Vg0 + (size_t)rowV*Ss + kv0 + scv*8, &Vs[bufi][rowV*64 + cV*8]);
    }
  };

  bf16x8 aq[4];
  {
    const int qr = q0 + w*16 + (lane & 15);
    const bf16* qp = Qb + ((size_t)(b*Ss + qr) * NHh + h) * HDd + (lane>>4)*8;
#pragma unroll
    for (int kc = 0; kc < 4; ++kc) aq[kc] = *(const bf16x8*)(qp + kc*32);
  }
  float m_i[4], l_par[4];
  f32x4 o[8] = {};
#pragma unroll
  for (int i = 0; i < 4; ++i) { m_i[i] = -1e30f; l_par[i] = 0.f; }

  stage(0, 0);
  asm volatile("s_waitcnt vmcnt(0)" ::: "memory");
  __builtin_amdgcn_s_barrier();
  asm volatile("" ::: "memory");

  const int NT = Ss / 64;
  for (int t = 0; t < NT; ++t) {
    const int cur = t & 1;
    if (t + 1 < NT) stage(cur ^ 1, (t + 1) * 64);

    f32x4 sf[4];
    __builtin_amdgcn_s_setprio(1);
#pragma unroll
    for (int nf = 0; nf < 4; ++nf) {
      f32x4 a = {0.f,0.f,0.f,0.f};
#pragma unroll
      for (int kc = 0; kc < 4; ++kc) {
        const int row = nf*16 + (lane & 15);
        const int ch  = kc*4 + (lane>>4);
        bf16x8 bk = *(const bf16x8*)&Ks[cur][row*128 + (ch ^ (row & 7))*8];
        a = MFMA16(aq[kc], bk, a);
      }
      sf[nf] = a;
    }
    __builtin_amdgcn_s_setprio(0);

    float xl[4];
#pragma unroll
    for (int i = 0; i < 4; ++i)
      xl[i] = fmaxf(fmaxf(sf[0][i], sf[1][i]), fmaxf(sf[2][i], sf[3][i]));
    bool grow = (xl[0] > m_i[0] + 11.5f) || (xl[1] > m_i[1] + 11.5f) ||
                (xl[2] > m_i[2] + 11.5f) || (xl[3] > m_i[3] + 11.5f);
    if (__any(grow)) {
#pragma unroll
      for (int i = 0; i < 4; ++i) {
        float x = xl[i];
        x = fmaxf(x, __shfl_xor(x, 1));
        x = fmaxf(x, __shfl_xor(x, 2));
        x = fmaxf(x, __shfl_xor(x, 4));
        x = fmaxf(x, __shfl_xor(x, 8));
        float mnew = fmaxf(m_i[i], x);
        float c = exp2f(m_i[i] - mnew);
        m_i[i] = mnew; l_par[i] *= c;
#pragma unroll
        for (int nfo = 0; nfo < 8; ++nfo) o[nfo][i] *= c;
      }
    }
#pragma unroll
    for (int nf = 0; nf < 4; ++nf)
#pragma unroll
      for (int i = 0; i < 4; ++i) {
        float pv = exp2f(sf[nf][i] - m_i[i]);
        sf[nf][i] = pv;
        l_par[i] += pv;
      }
#pragma unroll
    for (int nf = 0; nf < 4; ++nf)
#pragma unroll
      for (int i = 0; i < 4; ++i)
        Ps[(w*16 + (lane>>4)*4 + i)*72 + nf*16 + (lane & 15)] = (bf16)sf[nf][i];

    __builtin_amdgcn_s_setprio(1);
#pragma unroll
    for (int kc = 0; kc < 2; ++kc) {
      bf16x8 pa = *(const bf16x8*)&Ps[(w*16 + (lane & 15))*72 + kc*32 + (lane>>4)*8];
#pragma unroll
      for (int nfo = 0; nfo < 8; ++nfo) {
        const int row = nfo*16 + (lane & 15);
        const int ch  = kc*4 + (lane>>4);
        bf16x8 bv = *(const bf16x8*)&Vs[cur][row*64 + (ch ^ (row & 7))*8];
        o[nfo] = MFMA16(pa, bv, o[nfo]);
      }
    }
    __builtin_amdgcn_s_setprio(0);

    asm volatile("s_waitcnt vmcnt(0)" ::: "memory");
    __builtin_amdgcn_s_barrier();
    asm volatile("" ::: "memory");
  }

  float linv[4];
#pragma unroll
  for (int i = 0; i < 4; ++i) {
    float s = l_par[i];
    s += __shfl_xor(s, 1); s += __shfl_xor(s, 2);
    s += __shfl_xor(s, 4); s += __shfl_xor(s, 8);
    linv[i] = 1.0f / s;
  }
#pragma unroll
  for (int nfo = 0; nfo < 8; ++nfo)
#pragma unroll
    for (int i = 0; i < 4; ++i) {
      const int qr = q0 + w*16 + (lane>>4)*4 + i;
      const int d  = nfo*16 + (lane & 15);
      Ob[((size_t)(b*Ss + qr) * NHh + h) * HDd + d] = (bf16)(o[nfo][i] * linv[i]);
    }
}

// ---------------- launcher ----------------
extern "C" void kernel_launch(void* const* d_in, const int* in_sizes, int n_in,
                              void* d_out, int out_size, void* d_ws, size_t ws_size,
                              hipStream_t stream) {
  (void)in_sizes; (void)n_in; (void)out_size; (void)ws_size;
  const float* X  = (const float*)d_in[0];
  const float* Wq = (const float*)d_in[1];
  const float* Wk = (const float*)d_in[2];
  const float* Wv = (const float*)d_in[3];
  const float* Wo = (const float*)d_in[4];
  float* out = (float*)d_out;

  char* p = (char*)d_ws;
  size_t off = 0;
  auto take = [&](size_t bytes) { char* r = p + off; off += (bytes + 255) & ~(size_t)255; return r; };

  float* cosT = (float*)take((size_t)Ss*64*4);
  float* sinT = (float*)take((size_t)Ss*64*4);
  bf16*  Xb   = (bf16*) take((size_t)Mm*Hh*2);        // 16.8 MB
  bf16*  Wqkv = (bf16*) take((size_t)3*Hh*Hh*2);      // 25.2 MB [6144][2048]
  bf16*  Wob  = (bf16*) take((size_t)Hh*Hh*2);        //  8.4 MB
  bf16*  QKb  = (bf16*) take((size_t)Mm*4096*2);      // 33.6 MB [M][4096]
  bf16*  Vt   = (bf16*) take((size_t)Mm*Hh*2);        // 16.8 MB (B,NH,HD,S)
  bf16*  Qb   = (bf16*) take((size_t)Mm*Hh*2);
  bf16*  Kb2  = (bf16*) take((size_t)Mm*Hh*2);
  bf16*  Ob   = (bf16*) take((size_t)Mm*Hh*2);

  // 1. tables + casts (Wq/Wk/Wv concatenated row-wise into Wqkv)
  k_tables<<<(Ss*64)/256, 256, 0, stream>>>(cosT, sinT);
  k_cvt<<<(Mm*Hh)/4/256, 256, 0, stream>>>(X,  Xb);
  k_cvt<<<(Hh*Hh)/4/256, 256, 0, stream>>>(Wq, Wqkv);
  k_cvt<<<(Hh*Hh)/4/256, 256, 0, stream>>>(Wk, Wqkv + (size_t)Hh*Hh);
  k_cvt<<<(Hh*Hh)/4/256, 256, 0, stream>>>(Wv, Wqkv + (size_t)2*Hh*Hh);
  k_cvt<<<(Hh*Hh)/4/256, 256, 0, stream>>>(Wo, Wob);

  // 2. fused QKV projection (8-phase 256^2): Q,K -> QKb bf16; V -> Vt transposed bf16
  k_gemm8_qkv<<<(Mm/256) * (3*Hh/256), 512, 0, stream>>>(Xb, Wqkv, QKb, Vt);
  // 3. RoPE -> bf16 Q (scaled by log2e/sqrt(HD)), K
  k_rope<<<((size_t)Mm*NHh*64)/256, 256, 0, stream>>>(QKb, cosT, sinT, Qb, Kb2);
  // 4. attention
  k_attn<<<Bb*NHh*(Ss/64), 256, 0, stream>>>(Qb, Kb2, Vt, Ob);
  // 5. output projection -> d_out (fp32), m97 128^2 structure
  k_gemm_f32<<<(Mm/128) * (Hh/128), 256, 0, stream>>>(Ob, Wob, out, Mm, Hh, Hh);
}